// Round 7
// baseline (210.251 us; speedup 1.0000x reference)
//
#include <hip/hip_runtime.h>
#include <hip/hip_fp16.h>
#include <cstdint>

#define T_STEPS 32
#define NB 64
#define STATE 64
#define HID 128
#define ACT 32
#define CDIM 96
#define G3 (3*HID)   // 384

typedef __attribute__((ext_vector_type(8))) short short8;
typedef __attribute__((ext_vector_type(4))) float f32x4;
typedef _Float16 h2v __attribute__((ext_vector_type(2)));

__device__ __forceinline__ unsigned short f2bf(float f){
  unsigned int u = __builtin_bit_cast(unsigned int, f);
  u = u + 0x7FFFu + ((u >> 16) & 1u);
  return (unsigned short)(u >> 16);
}
__device__ __forceinline__ float bf2f(unsigned short u){
  unsigned int v = ((unsigned int)u) << 16; return __builtin_bit_cast(float, v);
}
__device__ __forceinline__ unsigned int packh2(float f0, float f1){
  return (unsigned int)__half_as_ushort(__float2half_rn(f0)) |
         ((unsigned int)__half_as_ushort(__float2half_rn(f1)) << 16);
}
__device__ __forceinline__ float sigmoidf_(float x){ return 1.0f/(1.0f + __expf(-x)); }
__device__ __forceinline__ float tanhf_(float x){ float e = __expf(2.0f*x); return (e-1.0f)/(e+1.0f); }

__device__ __forceinline__ float dot2f(float acc, unsigned int a, unsigned int b){
  h2v av = __builtin_bit_cast(h2v, a);
  h2v bv = __builtin_bit_cast(h2v, b);
  return __builtin_amdgcn_fdot2(av, bv, acc, false);
}
__device__ __forceinline__ float l1d(float acc, unsigned int ua, unsigned int ub){
  __half2 a = __builtin_bit_cast(__half2, ua);
  __half2 b = __builtin_bit_cast(__half2, ub);
  __half2 d = __habs2(__hsub2(a, b));
  h2v dv = __builtin_bit_cast(h2v, d);
  h2v ones; ones[0] = (_Float16)1.0f; ones[1] = (_Float16)1.0f;
  return __builtin_amdgcn_fdot2(dv, ones, acc, false);
}
__device__ __forceinline__ float l1d4(float acc, uint4 a, uint4 b){
  acc = l1d(acc, a.x, b.x); acc = l1d(acc, a.y, b.y);
  acc = l1d(acc, a.z, b.z); acc = l1d(acc, a.w, b.w);
  return acc;
}

// ---------------- prep ----------------
// 0..127   : tmh (Tm -> bf16 B-frag order per b)
// 128..131 : whh0p, whh1p fp16-packed [k2][r]
// 132..135 : w1f  (w1 -> bf16 B-frag, 20480)
// 136..137 : wih0p fp16-packed [k2<32][r]
// 138..141 : wih1p fp16-packed [k2<64][r]
// 142..153 : a -> bf16 A-frag chunks 16..19 of h1af
__global__ void k_prep(const float* __restrict__ Tm, unsigned short* __restrict__ tmh,
                       const float* __restrict__ whh0, const float* __restrict__ whh1,
                       const float* __restrict__ w1, const float* __restrict__ wih0,
                       const float* __restrict__ wih1, const float* __restrict__ a,
                       unsigned int* __restrict__ whh0p, unsigned int* __restrict__ whh1p,
                       unsigned short* __restrict__ w1f, unsigned int* __restrict__ wih0p,
                       unsigned int* __restrict__ wih1p, unsigned short* __restrict__ h1af){
  int tid = threadIdx.x;
  int bx = blockIdx.x;
  if (bx < 128){
    int b = bx;
    for (int e = tid; e < HID*CDIM; e += 256){
      int chunk = e / 768;
      int r1 = e - chunk*768;
      int c = r1 >> 3, h = r1 & 7;
      int k = chunk*8 + h;
      tmh[b*(HID*CDIM) + e] = f2bf(Tm[k*(HID*CDIM) + b*CDIM + c]);
    }
  } else if (bx < 132){
    for (int e = (bx-128)*256 + tid; e < 24576; e += 1024){
      int k2 = e / 384, r = e - k2*384;
      whh0p[e] = packh2(whh0[r*128 + 2*k2], whh0[r*128 + 2*k2 + 1]);
      whh1p[e] = packh2(whh1[r*128 + 2*k2], whh1[r*128 + 2*k2 + 1]);
    }
  } else if (bx < 136){
    for (int e = (bx-132)*256 + tid; e < 20480; e += 1024){
      int kc = e >> 10, rem = e & 1023;
      int col = rem >> 3, j = rem & 7;
      w1f[e] = f2bf(w1[col*160 + kc*8 + j]);
    }
  } else if (bx < 138){
    for (int e = (bx-136)*256 + tid; e < 12288; e += 512){
      int k2 = e / 384, r = e - k2*384;
      wih0p[e] = packh2(wih0[r*64 + 2*k2], wih0[r*64 + 2*k2 + 1]);
    }
  } else if (bx < 142){
    for (int e = (bx-138)*256 + tid; e < 24576; e += 1024){
      int k2 = e / 384, r = e - k2*384;
      wih1p[e] = packh2(wih1[r*128 + 2*k2], wih1[r*128 + 2*k2 + 1]);
    }
  } else {
    for (int e = (bx-142)*256 + tid; e < 65536; e += 3072){
      int t = e >> 11, rem = e & 2047;
      int n = rem >> 5, c = rem & 31;
      int pos = t*10240 + (n>>4)*2560 + (16 + (c>>3))*128 + (n&15)*8 + (c&7);
      h1af[pos] = f2bf(a[t*(NB*ACT) + n*ACT + c]);
    }
  }
}

// ---------------- GRU layer 0: recurrence + fused input projection (x staged in LDS) ----------------
// thread = (r = tid>>1, kh = tid&1). whh0 in 32 VGPRs, wih0 in 16. gi double-buffered in LDS.
__global__ __launch_bounds__(768, 3) void k_rec0(const float* __restrict__ x,
                                                 const unsigned int* __restrict__ wihp,
                                                 const unsigned int* __restrict__ whhp,
                                                 const float* __restrict__ bih, const float* __restrict__ bhh,
                                                 unsigned short* __restrict__ h0g){
  __shared__ __align__(16) unsigned int xall[1024];   // [t][32 h2]
  __shared__ __align__(16) unsigned int hl[64];
  __shared__ float A0[G3];
  __shared__ float GI[2][G3];
  int n = blockIdx.x, tid = threadIdx.x;
  int r = tid >> 1, kh = tid & 1;
  unsigned int wh[32], wi[16];
  #pragma unroll
  for (int i = 0; i < 32; i++) wh[i] = whhp[(kh*32 + i)*384 + r];
  #pragma unroll
  for (int i = 0; i < 16; i++) wi[i] = wihp[(kh*16 + i)*384 + r];
  float bh = (kh == 0) ? bhh[r] : 0.0f;
  float bi = (kh == 0) ? bih[r] : 0.0f;
  for (int e = tid; e < 1024; e += 768){
    int t_ = e >> 5, i = e & 31;
    const float* xp = x + t_*(NB*STATE) + n*STATE + 2*i;
    xall[e] = packh2(xp[0], xp[1]);
  }
  if (tid < 64) hl[tid] = 0u;
  float hprev = 0.0f;
  __syncthreads();
  const uint4* xl4 = (const uint4*)xall;
  const uint4* h4  = (const uint4*)hl;
  // prologue: gi[0]
  {
    float gi = bi;
    #pragma unroll
    for (int j = 0; j < 4; j++){
      uint4 xv = xl4[kh*4 + j];
      gi = dot2f(gi, wi[j*4 + 0], xv.x);
      gi = dot2f(gi, wi[j*4 + 1], xv.y);
      gi = dot2f(gi, wi[j*4 + 2], xv.z);
      gi = dot2f(gi, wi[j*4 + 3], xv.w);
    }
    gi += __shfl_xor(gi, 1);
    if (kh == 0) GI[0][r] = gi;
  }
  __syncthreads();
  for (int t = 0; t < T_STEPS; t++){
    float gh = bh, gin = bi;
    #pragma unroll
    for (int g = 0; g < 2; g++){
      uint4 hv[4];
      #pragma unroll
      for (int j = 0; j < 4; j++) hv[j] = h4[kh*8 + g*4 + j];
      #pragma unroll
      for (int j = 0; j < 4; j++){
        gh = dot2f(gh, wh[g*16 + j*4 + 0], hv[j].x);
        gh = dot2f(gh, wh[g*16 + j*4 + 1], hv[j].y);
        gh = dot2f(gh, wh[g*16 + j*4 + 2], hv[j].z);
        gh = dot2f(gh, wh[g*16 + j*4 + 3], hv[j].w);
      }
    }
    if (t + 1 < T_STEPS){
      #pragma unroll
      for (int j = 0; j < 4; j++){
        uint4 xv = xl4[(t+1)*8 + kh*4 + j];
        gin = dot2f(gin, wi[j*4 + 0], xv.x);
        gin = dot2f(gin, wi[j*4 + 1], xv.y);
        gin = dot2f(gin, wi[j*4 + 2], xv.z);
        gin = dot2f(gin, wi[j*4 + 3], xv.w);
      }
    }
    gh  += __shfl_xor(gh, 1);
    gin += __shfl_xor(gin, 1);
    if (kh == 0){
      A0[r] = gh;
      if (t + 1 < T_STEPS) GI[(t+1)&1][r] = gin;
    }
    __syncthreads();
    if (tid < HID){
      const float* gi = GI[t&1];
      float rg = sigmoidf_(gi[tid]       + A0[tid]);
      float z  = sigmoidf_(gi[tid+HID]   + A0[tid+HID]);
      float nn = tanhf_   (gi[tid+2*HID] + rg*A0[tid+2*HID]);
      float hn = (1.0f - z)*nn + z*hprev;
      hprev = hn;
      ((__half*)hl)[tid] = __float2half_rn(hn);
      h0g[n*4096 + t*128 + tid] = __half_as_ushort(__float2half_rn(hn));
    }
    __syncthreads();
  }
}

// ---------------- GRU layer 1: recurrence + fused input projection (h0 trajectory in LDS) ----------------
__global__ __launch_bounds__(768, 3) void k_rec1(const unsigned short* __restrict__ h0g,
                                                 const unsigned int* __restrict__ wihp,
                                                 const unsigned int* __restrict__ whhp,
                                                 const float* __restrict__ bih, const float* __restrict__ bhh,
                                                 unsigned short* __restrict__ h1af){
  __shared__ __align__(16) unsigned int h0all[2048];   // [t][64 h2]
  __shared__ __align__(16) unsigned int hl[64];
  __shared__ float A0[G3];
  __shared__ float GI[2][G3];
  int n = blockIdx.x, tid = threadIdx.x;
  int r = tid >> 1, kh = tid & 1;
  unsigned int wh[32], wi[32];
  #pragma unroll
  for (int i = 0; i < 32; i++) wh[i] = whhp[(kh*32 + i)*384 + r];
  #pragma unroll
  for (int i = 0; i < 32; i++) wi[i] = wihp[(kh*32 + i)*384 + r];
  float bh = (kh == 0) ? bhh[r] : 0.0f;
  float bi = (kh == 0) ? bih[r] : 0.0f;
  const unsigned int* h0u = (const unsigned int*)h0g;
  for (int e = tid; e < 2048; e += 768) h0all[e] = h0u[n*2048 + e];
  if (tid < 64) hl[tid] = 0u;
  float hprev = 0.0f;
  __syncthreads();
  const uint4* h0l4 = (const uint4*)h0all;
  const uint4* h4   = (const uint4*)hl;
  // prologue: gi[0] from h0[0]
  {
    float gi = bi;
    #pragma unroll
    for (int g = 0; g < 2; g++){
      #pragma unroll
      for (int j = 0; j < 4; j++){
        uint4 hv = h0l4[kh*8 + g*4 + j];
        gi = dot2f(gi, wi[g*16 + j*4 + 0], hv.x);
        gi = dot2f(gi, wi[g*16 + j*4 + 1], hv.y);
        gi = dot2f(gi, wi[g*16 + j*4 + 2], hv.z);
        gi = dot2f(gi, wi[g*16 + j*4 + 3], hv.w);
      }
    }
    gi += __shfl_xor(gi, 1);
    if (kh == 0) GI[0][r] = gi;
  }
  __syncthreads();
  for (int t = 0; t < T_STEPS; t++){
    float gh = bh, gin = bi;
    #pragma unroll
    for (int g = 0; g < 2; g++){
      uint4 hv[4];
      #pragma unroll
      for (int j = 0; j < 4; j++) hv[j] = h4[kh*8 + g*4 + j];
      #pragma unroll
      for (int j = 0; j < 4; j++){
        gh = dot2f(gh, wh[g*16 + j*4 + 0], hv[j].x);
        gh = dot2f(gh, wh[g*16 + j*4 + 1], hv[j].y);
        gh = dot2f(gh, wh[g*16 + j*4 + 2], hv[j].z);
        gh = dot2f(gh, wh[g*16 + j*4 + 3], hv[j].w);
      }
    }
    if (t + 1 < T_STEPS){
      #pragma unroll
      for (int g = 0; g < 2; g++){
        #pragma unroll
        for (int j = 0; j < 4; j++){
          uint4 hv = h0l4[(t+1)*16 + kh*8 + g*4 + j];
          gin = dot2f(gin, wi[g*16 + j*4 + 0], hv.x);
          gin = dot2f(gin, wi[g*16 + j*4 + 1], hv.y);
          gin = dot2f(gin, wi[g*16 + j*4 + 2], hv.z);
          gin = dot2f(gin, wi[g*16 + j*4 + 3], hv.w);
        }
      }
    }
    gh  += __shfl_xor(gh, 1);
    gin += __shfl_xor(gin, 1);
    if (kh == 0){
      A0[r] = gh;
      if (t + 1 < T_STEPS) GI[(t+1)&1][r] = gin;
    }
    __syncthreads();
    if (tid < HID){
      const float* gi = GI[t&1];
      float rg = sigmoidf_(gi[tid]       + A0[tid]);
      float z  = sigmoidf_(gi[tid+HID]   + A0[tid+HID]);
      float nn = tanhf_   (gi[tid+2*HID] + rg*A0[tid+2*HID]);
      float hn = (1.0f - z)*nn + z*hprev;
      hprev = hn;
      ((__half*)hl)[tid] = __float2half_rn(hn);
      h1af[t*10240 + (n>>4)*2560 + (tid>>3)*128 + (n&15)*8 + (tid&7)] = f2bf(hn);
    }
    __syncthreads();
  }
}

// ---------------- fc1: t-parallel MFMA, A = [h1;a] frags, B = w1 frags ----------------
__global__ __launch_bounds__(256) void k_fc1(const unsigned short* __restrict__ h1af,
                                             const unsigned short* __restrict__ w1f,
                                             const float* __restrict__ b1,
                                             unsigned short* __restrict__ fc1h){
  __shared__ float b1s[128];
  int t = blockIdx.x, tid = threadIdx.x;
  int wave = tid >> 6, lane = tid & 63, m = lane & 15, quad = lane >> 4;
  if (tid < 128) b1s[tid] = b1[tid];
  const uint4* A4 = (const uint4*)(h1af + t*10240);
  const uint4* B4 = (const uint4*)w1f;
  f32x4 acc[8];
  #pragma unroll
  for (int i = 0; i < 8; i++) acc[i] = (f32x4)(0.0f);
  #pragma unroll
  for (int ks = 0; ks < 5; ks++){
    uint4 av = A4[wave*320 + (ks*4 + quad)*16 + m];
    short8 avs = __builtin_bit_cast(short8, av);
    #pragma unroll
    for (int nt = 0; nt < 8; nt++){
      uint4 bv = B4[(ks*4 + quad)*128 + nt*16 + m];
      acc[nt] = __builtin_amdgcn_mfma_f32_16x16x32_bf16(avs, __builtin_bit_cast(short8, bv), acc[nt], 0, 0, 0);
    }
  }
  __syncthreads();
  #pragma unroll
  for (int nt = 0; nt < 8; nt++){
    float bj = b1s[nt*16 + m];
    #pragma unroll
    for (int rr = 0; rr < 4; rr++){
      float v = fmaxf(acc[nt][rr] + bj, 0.0f);
      fc1h[t*8192 + wave*2048 + (nt*2 + (m>>3))*128 + (quad*4 + rr)*8 + (m&7)] = f2bf(v);
    }
  }
}

// ---------------- minibatch discrimination: one block per (b, 4 t's), double-buffered ----------------
__global__ __launch_bounds__(256) void k_disc(const unsigned short* __restrict__ fc1h,
                                              const unsigned short* __restrict__ tmh,
                                              float* __restrict__ O){
  __shared__ __align__(16) __half Mh[2][64*104];
  __shared__ float ps[2][64*18];
  int b = blockIdx.x;
  int tid = threadIdx.x;
  int wave = tid >> 6, lane = tid & 63, m = lane & 15, quad = lane >> 4;
  int t0 = blockIdx.y*4;
  const uint4* Bg = (const uint4*)(tmh + b*(CDIM*HID));
  uint4 a4[4];
  #pragma unroll
  for (int kk = 0; kk < 4; kk++) a4[kk] = ((const uint4*)(fc1h + t0*8192))[wave*256 + (kk*4 + quad)*16 + m];
  #pragma unroll 1
  for (int tt = 0; tt < 4; tt++){
    int p = tt & 1;
    int t = t0 + tt;
    f32x4 acc[6];
    #pragma unroll
    for (int i = 0; i < 6; i++) acc[i] = (f32x4)(0.0f);
    #pragma unroll
    for (int kk = 0; kk < 4; kk++){
      short8 av = __builtin_bit_cast(short8, a4[kk]);
      #pragma unroll
      for (int nt = 0; nt < 6; nt++){
        uint4 b4 = Bg[(kk*4 + quad)*96 + nt*16 + m];
        acc[nt] = __builtin_amdgcn_mfma_f32_16x16x32_bf16(av, __builtin_bit_cast(short8, b4), acc[nt], 0, 0, 0);
      }
    }
    if (tt < 3){   // prefetch next t's A frags (overlaps Mh writes + barrier + pairwise start)
      #pragma unroll
      for (int kk = 0; kk < 4; kk++) a4[kk] = ((const uint4*)(fc1h + (t+1)*8192))[wave*256 + (kk*4 + quad)*16 + m];
    }
    #pragma unroll
    for (int nt = 0; nt < 6; nt++){
      #pragma unroll
      for (int rr = 0; rr < 4; rr++){
        Mh[p][(rr*16 + wave*4 + quad)*104 + nt*16 + m] = __float2half(acc[nt][rr]);
      }
    }
    __syncthreads();   // Mh[p] ready; everyone past pairwise(tt-1); ps[1-p] stable
    if (tt > 0 && tid < NB){
      float s = 0.0f;
      #pragma unroll
      for (int k = 0; k < 16; k++) s += ps[1-p][tid*18 + k];
      O[((t-1)*HID + b)*NB + tid] = s*(1.0f/63.0f);
    }
    const uint4* M4 = (const uint4*)Mh[p];
    if (tid < 240){
      int chalf = tid & 1, tp = tid >> 1;
      int rnd = tp >> 3, slot = tp & 7;
      int ta, tb;
      if (slot == 0){ ta = 15; tb = rnd; }
      else {
        ta = rnd + slot;      if (ta >= 15) ta -= 15;
        tb = rnd + 15 - slot; if (tb >= 15) tb -= 15;
      }
      float facc[16];
      #pragma unroll
      for (int pp = 0; pp < 16; pp++) facc[pp] = 0.0f;
      auto doChunk = [&](int c){
        int ch = chalf*6 + c;
        uint4 av[4], bv[4];
        #pragma unroll
        for (int s = 0; s < 4; s++){
          av[s] = M4[(s*16 + ta)*13 + ch];
          bv[s] = M4[(s*16 + tb)*13 + ch];
        }
        #pragma unroll
        for (int i = 0; i < 4; i++)
          #pragma unroll
          for (int j = 0; j < 4; j++)
            facc[i*4+j] = l1d4(facc[i*4+j], av[i], bv[j]);
      };
      doChunk(0); doChunk(1);
      bool big1 = true;
      #pragma unroll
      for (int pp = 0; pp < 16; pp++) big1 = big1 && (facc[pp] > 14.0f);
      if (!big1){
        doChunk(2); doChunk(3);
        bool big2 = true;
        #pragma unroll
        for (int pp = 0; pp < 16; pp++) big2 = big2 && (facc[pp] > 14.0f);
        if (!big2){ doChunk(4); doChunk(5); }
      }
      float tot[16];
      #pragma unroll
      for (int pp = 0; pp < 16; pp++) tot[pp] = facc[pp] + __shfl_xor(facc[pp], 1);
      if (chalf == 0){
        #pragma unroll
        for (int i = 0; i < 4; i++){
          float s = 0.0f;
          #pragma unroll
          for (int j = 0; j < 4; j++) s += __expf(-tot[i*4+j]);
          ps[p][(ta*4 + i)*18 + tb] = s;
        }
      } else {
        #pragma unroll
        for (int j = 0; j < 4; j++){
          float s = 0.0f;
          #pragma unroll
          for (int i = 0; i < 4; i++) s += __expf(-tot[i*4+j]);
          ps[p][(tb*4 + j)*18 + ta] = s;
        }
      }
    } else {
      int ta = tid - 240;
      float f6[6];
      #pragma unroll
      for (int pp = 0; pp < 6; pp++) f6[pp] = 0.0f;
      auto doChunkS = [&](int ch){
        uint4 rv[4];
        #pragma unroll
        for (int s = 0; s < 4; s++) rv[s] = M4[(s*16 + ta)*13 + ch];
        f6[0] = l1d4(f6[0], rv[0], rv[1]);
        f6[1] = l1d4(f6[1], rv[0], rv[2]);
        f6[2] = l1d4(f6[2], rv[0], rv[3]);
        f6[3] = l1d4(f6[3], rv[1], rv[2]);
        f6[4] = l1d4(f6[4], rv[1], rv[3]);
        f6[5] = l1d4(f6[5], rv[2], rv[3]);
      };
      doChunkS(0); doChunkS(1); doChunkS(2);
      bool big1 = true;
      #pragma unroll
      for (int pp = 0; pp < 6; pp++) big1 = big1 && (f6[pp] > 14.0f);
      if (!big1){
        doChunkS(3); doChunkS(4); doChunkS(5);
        bool big2 = true;
        #pragma unroll
        for (int pp = 0; pp < 6; pp++) big2 = big2 && (f6[pp] > 14.0f);
        if (!big2){
          doChunkS(6); doChunkS(7); doChunkS(8);
          doChunkS(9); doChunkS(10); doChunkS(11);
        }
      }
      float e01 = __expf(-f6[0]), e02 = __expf(-f6[1]), e03 = __expf(-f6[2]);
      float e12 = __expf(-f6[3]), e13 = __expf(-f6[4]), e23 = __expf(-f6[5]);
      ps[p][(ta*4 + 0)*18 + ta] = e01 + e02 + e03;
      ps[p][(ta*4 + 1)*18 + ta] = e01 + e12 + e13;
      ps[p][(ta*4 + 2)*18 + ta] = e02 + e12 + e23;
      ps[p][(ta*4 + 3)*18 + ta] = e03 + e13 + e23;
    }
  }
  __syncthreads();
  if (tid < NB){
    float s = 0.0f;
    #pragma unroll
    for (int k = 0; k < 16; k++) s += ps[1][tid*18 + k];
    O[((t0+3)*HID + b)*NB + tid] = s*(1.0f/63.0f);
  }
}

// ---------------- final: reads fc1 bf16 frags + O ----------------
__global__ __launch_bounds__(256) void k_final(const unsigned short* __restrict__ fc1h,
                                               const float* __restrict__ O,
                                               const float* __restrict__ w2, const float* __restrict__ b2,
                                               float* __restrict__ out){
  __shared__ float ol[NB*HID];            // [b][n]
  __shared__ unsigned short fr[8192];
  __shared__ float wl[2*HID + 2];
  int t = blockIdx.x, tid = threadIdx.x;
  for (int i = tid; i < NB*HID; i += 256) ol[i] = O[t*NB*HID + i];
  const uint4* Fg = (const uint4*)(fc1h + t*8192);
  for (int i = tid; i < 1024; i += 256) ((uint4*)fr)[i] = Fg[i];
  if (tid < 2*HID) wl[tid] = w2[tid];
  if (tid == 0) wl[2*HID] = b2[0];
  __syncthreads();
  if (tid < NB){
    float acc = wl[2*HID];
    int base = (tid>>4)*2048 + (tid&15)*8;
    #pragma unroll 8
    for (int j = 0; j < HID; j++) acc += bf2f(fr[base + (j>>3)*128 + (j&7)])*wl[j];
    #pragma unroll 8
    for (int b = 0; b < HID; b++) acc += ol[b*NB + tid]*wl[HID + b];
    out[t*NB + tid] = sigmoidf_(acc);
  }
}

extern "C" void kernel_launch(void* const* d_in, const int* in_sizes, int n_in,
                              void* d_out, int out_size, void* d_ws, size_t ws_size,
                              hipStream_t stream){
  const float* x    = (const float*)d_in[0];
  const float* a    = (const float*)d_in[1];
  const float* wih0 = (const float*)d_in[2];
  const float* whh0 = (const float*)d_in[3];
  const float* bih0 = (const float*)d_in[4];
  const float* bhh0 = (const float*)d_in[5];
  const float* wih1 = (const float*)d_in[6];
  const float* whh1 = (const float*)d_in[7];
  const float* bih1 = (const float*)d_in[8];
  const float* bhh1 = (const float*)d_in[9];
  const float* w1   = (const float*)d_in[10];
  const float* b1   = (const float*)d_in[11];
  const float* w2   = (const float*)d_in[12];
  const float* b2   = (const float*)d_in[13];
  const float* Tm   = (const float*)d_in[14];
  float* ws = (float*)d_ws;
  float* Ows = ws;                                          // 262144 floats
  unsigned int* whh0p = (unsigned int*)(ws + 262144);       // 24576 dwords
  unsigned int* whh1p = (unsigned int*)(ws + 286720);       // 24576
  unsigned int* wih0p = (unsigned int*)(ws + 311296);       // 12288
  unsigned int* wih1p = (unsigned int*)(ws + 323584);       // 24576
  unsigned short* tmh  = (unsigned short*)(ws + 348160);    // 1572864 ushorts
  unsigned short* fc1h = (unsigned short*)(ws + 1134592);   // 262144 ushorts
  unsigned short* h1af = (unsigned short*)(ws + 1265664);   // 327680 ushorts
  unsigned short* w1f  = (unsigned short*)(ws + 1429504);   // 20480 ushorts
  unsigned short* h0g  = (unsigned short*)(ws + 1439744);   // 262144 ushorts
  float* out = (float*)d_out;

  k_prep<<<dim3(154), dim3(256), 0, stream>>>(Tm, tmh, whh0, whh1, w1, wih0, wih1, a,
                                              whh0p, whh1p, w1f, wih0p, wih1p, h1af);
  k_rec0<<<dim3(NB), dim3(768), 0, stream>>>(x, wih0p, whh0p, bih0, bhh0, h0g);
  k_rec1<<<dim3(NB), dim3(768), 0, stream>>>(h0g, wih1p, whh1p, bih1, bhh1, h1af);
  k_fc1<<<dim3(T_STEPS), dim3(256), 0, stream>>>(h1af, w1f, b1, fc1h);
  k_disc<<<dim3(HID, T_STEPS/4), dim3(256), 0, stream>>>(fc1h, tmh, Ows);
  k_final<<<dim3(T_STEPS), dim3(256), 0, stream>>>(fc1h, Ows, w2, b2, out);
}